// Round 8
// baseline (384.076 us; speedup 1.0000x reference)
//
#include <hip/hip_runtime.h>

typedef unsigned short u16;
typedef unsigned int   u32;
typedef unsigned long long u64;
typedef __attribute__((ext_vector_type(4))) int   i32x4;
typedef __attribute__((ext_vector_type(4))) float f32x4;
typedef __attribute__((ext_vector_type(8))) short s16x8;

#define NROWS 98304L   // B*A
#define LDF   512      // feat row stride (250 h | 6 pad | 250 gat | 6 pad)

__device__ __forceinline__ u16 f2bf(float x) {
  union { float f; u32 u; } v; v.f = x;
  return (u16)((v.u + 0x7FFFu + ((v.u >> 16) & 1u)) >> 16);
}
__device__ __forceinline__ float bf2f(u16 b) {
  union { float f; u32 u; } v; v.u = ((u32)b) << 16;
  return v.f;
}

// async global->LDS, 16B per lane; LDS dest = wave-uniform base + lane*16 (m104)
__device__ __forceinline__ void gload_lds16(const u16* g, u16* l) {
  __builtin_amdgcn_global_load_lds(
      (const __attribute__((address_space(1))) unsigned int*)g,
      (__attribute__((address_space(3))) unsigned int*)l, 16, 0, 0);
}

// ---------------- weight prep: transpose + zero-pad to bf16 ----------------
// Wgat_t rows e=250/251 get u_l[h]=W_gat[h]@a_l[h], u_r[h] so the Wh GEMM
// emits el/er as free output columns (el = h . (W_gat @ a_l)).
__global__ __launch_bounds__(256)
void prep_weights(const float* __restrict__ W_emb, const float* __restrict__ b_emb,
                  const float* __restrict__ W_gat, const float* __restrict__ a_l,
                  const float* __restrict__ a_r, const float* __restrict__ W1,
                  const float* __restrict__ b1, const float* __restrict__ V1,
                  const float* __restrict__ vb1,
                  u16* __restrict__ Wemb_t, u16* __restrict__ Wgat_t,
                  u16* __restrict__ W1V1_t, float* __restrict__ bembp,
                  float* __restrict__ b1vb1)
{
  const int idx = blockIdx.x * 256 + threadIdx.x;
  const int stride = gridDim.x * 256;
  // Wemb_t[n][k], n<256 (pad 250..255), k<128
  for (int t = idx; t < 256 * 128; t += stride) {
    int n = t >> 7, k = t & 127;
    Wemb_t[t] = f2bf(n < 250 ? W_emb[k * 250 + n] : 0.f);
  }
  // Wgat_t[h][e][d] = W_gat[h][d][e] (256x256 padded); rows 250/251 = u_l/u_r
  for (int t = idx; t < 3 * 256 * 256; t += stride) {
    int h = t >> 16, rem = t & 65535, e = rem >> 8, d = rem & 255;
    float v = 0.f;
    if (e < 250 && d < 250) {
      v = W_gat[(h * 250 + d) * 250 + e];
    } else if ((e == 250 || e == 251) && d < 250) {
      const float* av = ((e == 250) ? a_l : a_r) + h * 250;
      const float* wrow = W_gat + ((long)h * 250 + d) * 250;
      float s = 0.f;
      for (int q = 0; q < 250; q++) s += wrow[q] * av[q];
      v = s;
    }
    Wgat_t[t] = f2bf(v);
  }
  // W1V1_t[n][k]: n<256 actor col, else critic col; k maps feat-pad rows
  for (int t = idx; t < 512 * 512; t += stride) {
    int n = t >> 9, k = t & 511;
    const float* src = (n < 256) ? W1 : V1;
    int col = n & 255;
    float v = 0.f;
    if (k < 250) v = src[k * 256 + col];
    else if (k >= 256 && k < 506) v = src[(k - 6) * 256 + col];
    W1V1_t[t] = f2bf(v);
  }
  for (int t = idx; t < 512; t += stride) b1vb1[t] = (t < 256) ? b1[t] : vb1[t - 256];
  for (int t = idx; t < 256; t += stride) bembp[t] = (t < 250) ? b_emb[t] : 0.f;
}

// ---------------- gemm1f: fused x(fp32)->bf16 + embed GEMM ----------------
// C[128 x 128] tile of feat = relu(x @ Wemb_t^T + b). A reg-staged from fp32
// with conversion + swizzled ds_write (LDS[row][s] = chunk s^(row&7), same
// invariant as gload path); B via global_load_lds. grid (768, 2) m-fast.
__global__ __launch_bounds__(256, 2)
void gemm1f(const float* __restrict__ X,          // [NROWS][128] fp32
            const u16* __restrict__ B,            // Wemb_t [256][128]
            u16* __restrict__ C,                  // feat, ldc=512
            const float* __restrict__ bias)       // bembp [256]
{
  __shared__ __align__(16) u16 At[128 * 64];
  __shared__ __align__(16) u16 Bt[128 * 64];
  const int tid = threadIdx.x;
  const int w = tid >> 6, lane = tid & 63;
  const int fl = lane & 15, fh = lane >> 4;
  const int wr = (w >> 1) * 64, wc = (w & 1) * 64;
  const int srow = lane >> 3;                    // 0..7
  const int slot = lane & 7;                     // 0..7
  const int schunk = ((slot ^ srow) << 3);       // source chunk (elems)
  const int swz = (fl & 7) << 3;

  const int midx = blockIdx.x;                   // 0..767
  const int nidx = blockIdx.y;                   // 0..1

  const float* Ax = X + (long)midx * 128 * 128;
  const u16* Bb = B + nidx * 128 * 128;
  u16* Cb = C + (long)midx * 128 * LDF + nidx * 128;
  const float* biasb = bias + nidx * 128;

  f32x4 acc[4][4];
  #pragma unroll
  for (int m = 0; m < 4; m++)
    #pragma unroll
    for (int n = 0; n < 4; n++)
      acc[m][n] = f32x4{0.f, 0.f, 0.f, 0.f};

  for (int ks = 0; ks < 2; ks++) {
    __syncthreads();
    #pragma unroll
    for (int c = 0; c < 4; c++) {
      const int row = w * 32 + c * 8 + srow;
      // B: async global->LDS
      gload_lds16(Bb + (long)row * 128 + ks * 64 + schunk, Bt + (w * 4 + c) * 512);
      // A: fp32 load -> bf16 pack -> swizzled ds_write
      const float* src = Ax + (long)row * 128 + ks * 64 + schunk;
      f32x4 lo = *(const f32x4*)src;
      f32x4 hi = *(const f32x4*)(src + 4);
      i32x4 o;
      o[0] = (int)((u32)f2bf(lo[0]) | ((u32)f2bf(lo[1]) << 16));
      o[1] = (int)((u32)f2bf(lo[2]) | ((u32)f2bf(lo[3]) << 16));
      o[2] = (int)((u32)f2bf(hi[0]) | ((u32)f2bf(hi[1]) << 16));
      o[3] = (int)((u32)f2bf(hi[2]) | ((u32)f2bf(hi[3]) << 16));
      *(i32x4*)(At + row * 64 + slot * 8) = o;
    }
    __syncthreads();
    #pragma unroll
    for (int kk = 0; kk < 2; kk++) {
      s16x8 af[4], bfr[4];
      #pragma unroll
      for (int m = 0; m < 4; m++)
        af[m] = *(const s16x8*)(At + (wr + m * 16 + fl) * 64 + ((kk * 32 + fh * 8) ^ swz));
      #pragma unroll
      for (int n = 0; n < 4; n++)
        bfr[n] = *(const s16x8*)(Bt + (wc + n * 16 + fl) * 64 + ((kk * 32 + fh * 8) ^ swz));
      #pragma unroll
      for (int m = 0; m < 4; m++)
        #pragma unroll
        for (int n = 0; n < 4; n++)
          acc[m][n] = __builtin_amdgcn_mfma_f32_16x16x32_bf16(af[m], bfr[n], acc[m][n], 0, 0, 0);
    }
  }
  #pragma unroll
  for (int m = 0; m < 4; m++) {
    const int r0 = wr + m * 16 + fh * 4;
    #pragma unroll
    for (int n = 0; n < 4; n++) {
      const int col = wc + n * 16 + fl;
      const float bvv = biasb[col];
      f32x4 v = acc[m][n];
      #pragma unroll
      for (int r = 0; r < 4; r++)
        Cb[(long)(r0 + r) * LDF + col] = f2bf(fmaxf(v[r] + bvv, 0.f));
    }
  }
}

// ---------------- bf16 GEMM (gemm2): C = A * Bt^T, raw bf16 store ----------
// BM=BN=128, BK=64, 256 threads. grid (768, nz*2) m-fast: x=m-tile (stream),
// y -> (zidx, nidx). global_load_lds staging, both-sides XOR swizzle.
template<int KSTEPS>
__global__ __launch_bounds__(256, 2)
void gemm_bf16(const u16* __restrict__ A, int lda,
               const u16* __restrict__ B, int ldb, long strideB,
               u16* __restrict__ C, int ldc, long strideC)
{
  __shared__ __align__(16) u16 At[128 * 64];
  __shared__ __align__(16) u16 Bt[128 * 64];
  const int tid = threadIdx.x;
  const int w = tid >> 6, lane = tid & 63;
  const int fl = lane & 15, fh = lane >> 4;
  const int wr = (w >> 1) * 64, wc = (w & 1) * 64;
  const int srow = lane >> 3;
  const int scol = (((lane & 7) ^ srow) << 3);
  const int swz = (fl & 7) << 3;

  const int midx = blockIdx.x;
  const int nidx = blockIdx.y & 1;
  const int zidx = blockIdx.y >> 1;

  const u16* Ab = A + (long)midx * 128 * lda;
  const u16* Bb = B + (long)zidx * strideB + (long)nidx * 128 * ldb;
  u16* Cb = C + (long)zidx * strideC + (long)midx * 128 * ldc + nidx * 128;

  f32x4 acc[4][4];
  #pragma unroll
  for (int m = 0; m < 4; m++)
    #pragma unroll
    for (int n = 0; n < 4; n++)
      acc[m][n] = f32x4{0.f, 0.f, 0.f, 0.f};

  for (int ks = 0; ks < KSTEPS; ks++) {
    __syncthreads();
    #pragma unroll
    for (int c = 0; c < 4; c++) {
      const int row = w * 32 + c * 8 + srow;
      gload_lds16(Ab + (long)row * lda + ks * 64 + scol, At + (w * 4 + c) * 512);
      gload_lds16(Bb + (long)row * ldb + ks * 64 + scol, Bt + (w * 4 + c) * 512);
    }
    __syncthreads();
    #pragma unroll
    for (int kk = 0; kk < 2; kk++) {
      s16x8 af[4], bfr[4];
      #pragma unroll
      for (int m = 0; m < 4; m++)
        af[m] = *(const s16x8*)(At + (wr + m * 16 + fl) * 64 + ((kk * 32 + fh * 8) ^ swz));
      #pragma unroll
      for (int n = 0; n < 4; n++)
        bfr[n] = *(const s16x8*)(Bt + (wc + n * 16 + fl) * 64 + ((kk * 32 + fh * 8) ^ swz));
      #pragma unroll
      for (int m = 0; m < 4; m++)
        #pragma unroll
        for (int n = 0; n < 4; n++)
          acc[m][n] = __builtin_amdgcn_mfma_f32_16x16x32_bf16(af[m], bfr[n], acc[m][n], 0, 0, 0);
    }
  }
  #pragma unroll
  for (int m = 0; m < 4; m++) {
    const int r0 = wr + m * 16 + fh * 4;
    #pragma unroll
    for (int n = 0; n < 4; n++) {
      const int col = wc + n * 16 + fl;
      f32x4 v = acc[m][n];
      #pragma unroll
      for (int r = 0; r < 4; r++)
        Cb[(long)(r0 + r) * ldc + col] = f2bf(v[r]);
    }
  }
}

// ---------------- gemm3p: feat @ [W1|V1] with partial-heads epilogue -------
// 128x128 GEMM, double-buffered K-loop (stage t+1 issued before compute t,
// ONE __syncthreads per K-step: its implicit vmcnt(0)+lgkmcnt(0) drain covers
// both RAW on next buf and WAR on re-staged buf). hid stays in regs; epilogue
// does relu+bias, partial dots with W2/V2, 16-lane reduce, LDS stage,
// writes partials[nidx][row][6]. grid (768, 4) m-fast.
__global__ __launch_bounds__(256, 2)
void gemm3p(const u16* __restrict__ A,            // feat [NROWS][512]
            const u16* __restrict__ B,            // W1V1_t [512][512]
            const float* __restrict__ b1vb1,      // [512]
            const float* __restrict__ W2,         // [256][5]
            const float* __restrict__ V2,         // [256]
            float* __restrict__ partials)         // [4][NROWS][6]
{
  __shared__ __align__(16) u16 At[2][128 * 64];
  __shared__ __align__(16) u16 Bt[2][128 * 64];
  __shared__ float pstage[2][128][6];
  const int tid = threadIdx.x;
  const int w = tid >> 6, lane = tid & 63;
  const int fl = lane & 15, fh = lane >> 4;
  const int wr = (w >> 1) * 64, wc = (w & 1) * 64;
  const int wcid = w & 1;
  const int srow = lane >> 3;
  const int scol = (((lane & 7) ^ srow) << 3);
  const int swz = (fl & 7) << 3;

  const int midx = blockIdx.x;                   // 0..767
  const int nidx = blockIdx.y;                   // 0..3

  const u16* Ab = A + (long)midx * 128 * 512;
  const u16* Bb = B + (long)nidx * 128 * 512;

  f32x4 acc[4][4];
  #pragma unroll
  for (int m = 0; m < 4; m++)
    #pragma unroll
    for (int n = 0; n < 4; n++)
      acc[m][n] = f32x4{0.f, 0.f, 0.f, 0.f};

  // prologue: stage K-step 0 into buf 0
  #pragma unroll
  for (int c = 0; c < 4; c++) {
    const int row = w * 32 + c * 8 + srow;
    gload_lds16(Ab + (long)row * 512 + scol, At[0] + (w * 4 + c) * 512);
    gload_lds16(Bb + (long)row * 512 + scol, Bt[0] + (w * 4 + c) * 512);
  }
  __syncthreads();

  for (int ks = 0; ks < 8; ks++) {
    const int cur = ks & 1;
    if (ks < 7) {              // issue next-tile loads BEFORE compute
      #pragma unroll
      for (int c = 0; c < 4; c++) {
        const int row = w * 32 + c * 8 + srow;
        gload_lds16(Ab + (long)row * 512 + (ks + 1) * 64 + scol, At[cur ^ 1] + (w * 4 + c) * 512);
        gload_lds16(Bb + (long)row * 512 + (ks + 1) * 64 + scol, Bt[cur ^ 1] + (w * 4 + c) * 512);
      }
    }
    #pragma unroll
    for (int kk = 0; kk < 2; kk++) {
      s16x8 af[4], bfr[4];
      #pragma unroll
      for (int m = 0; m < 4; m++)
        af[m] = *(const s16x8*)(At[cur] + (wr + m * 16 + fl) * 64 + ((kk * 32 + fh * 8) ^ swz));
      #pragma unroll
      for (int n = 0; n < 4; n++)
        bfr[n] = *(const s16x8*)(Bt[cur] + (wc + n * 16 + fl) * 64 + ((kk * 32 + fh * 8) ^ swz));
      #pragma unroll
      for (int m = 0; m < 4; m++)
        #pragma unroll
        for (int n = 0; n < 4; n++)
          acc[m][n] = __builtin_amdgcn_mfma_f32_16x16x32_bf16(af[m], bfr[n], acc[m][n], 0, 0, 0);
    }
    __syncthreads();           // drains vmcnt(0)+lgkmcnt(0): next buf ready, cur re-stageable
  }

  // ---- partial-heads epilogue ----
  float bv[4];
  #pragma unroll
  for (int n = 0; n < 4; n++) bv[n] = b1vb1[nidx * 128 + wc + n * 16 + fl];

  if (nidx < 2) {          // actor: hid cols nidx*128 + [0,128)
    #pragma unroll
    for (int m = 0; m < 4; m++) {
      float ps[4][5];
      #pragma unroll
      for (int r = 0; r < 4; r++)
        #pragma unroll
        for (int j = 0; j < 5; j++) ps[r][j] = 0.f;
      #pragma unroll
      for (int n = 0; n < 4; n++) {
        const int gcol = nidx * 128 + wc + n * 16 + fl;
        float w2r[5];
        #pragma unroll
        for (int j = 0; j < 5; j++) w2r[j] = W2[gcol * 5 + j];
        #pragma unroll
        for (int r = 0; r < 4; r++) {
          float hid = fmaxf(acc[m][n][r] + bv[n], 0.f);
          #pragma unroll
          for (int j = 0; j < 5; j++) ps[r][j] += hid * w2r[j];
        }
      }
      #pragma unroll
      for (int off = 1; off < 16; off <<= 1)
        #pragma unroll
        for (int r = 0; r < 4; r++)
          #pragma unroll
          for (int j = 0; j < 5; j++) ps[r][j] += __shfl_xor(ps[r][j], off, 16);
      if (fl == 0) {
        const int row = wr + m * 16 + fh * 4;
        #pragma unroll
        for (int r = 0; r < 4; r++)
          #pragma unroll
          for (int j = 0; j < 5; j++) pstage[wcid][row + r][j] = ps[r][j];
      }
    }
  } else {                 // critic: hid cols nidx*128 + [0,128) - 256
    #pragma unroll
    for (int m = 0; m < 4; m++) {
      float ps[4];
      #pragma unroll
      for (int r = 0; r < 4; r++) ps[r] = 0.f;
      #pragma unroll
      for (int n = 0; n < 4; n++) {
        const int gcol = nidx * 128 + wc + n * 16 + fl - 256;
        const float v2c = V2[gcol];
        #pragma unroll
        for (int r = 0; r < 4; r++)
          ps[r] += fmaxf(acc[m][n][r] + bv[n], 0.f) * v2c;
      }
      #pragma unroll
      for (int off = 1; off < 16; off <<= 1)
        #pragma unroll
        for (int r = 0; r < 4; r++) ps[r] += __shfl_xor(ps[r], off, 16);
      if (fl == 0) {
        const int row = wr + m * 16 + fh * 4;
        #pragma unroll
        for (int r = 0; r < 4; r++) pstage[wcid][row + r][5] = ps[r];
      }
    }
  }
  __syncthreads();

  if (tid < 128) {
    float* dst = partials + ((long)nidx * NROWS + (long)midx * 128 + tid) * 6;
    if (nidx < 2) {
      #pragma unroll
      for (int j = 0; j < 5; j++)
        dst[j] = pstage[0][tid][j] + pstage[1][tid][j];
    } else {
      dst[5] = pstage[0][tid][5] + pstage[1][tid][5];
    }
  }
}

// ---------------- heads_final: sum partials, softmax | value ---------------
__global__ __launch_bounds__(256)
void heads_final(const float* __restrict__ partials, const float* __restrict__ b2,
                 const float* __restrict__ vb2, float* __restrict__ out)
{
  const long row = (long)blockIdx.x * 256 + threadIdx.x;
  const long slab = NROWS * 6;
  const float* p = partials + row * 6;
  float lg[5];
  #pragma unroll
  for (int j = 0; j < 5; j++) lg[j] = p[j] + p[slab + j] + b2[j];
  const float val = p[2 * slab + 5] + p[3 * slab + 5] + vb2[0];
  float mx = -1e30f;
  #pragma unroll
  for (int j = 0; j < 5; j++) mx = fmaxf(mx, lg[j]);
  float s = 0.f, e[5];
  #pragma unroll
  for (int j = 0; j < 5; j++) { e[j] = __expf(lg[j] - mx); s += e[j]; }
  const float inv = 1.f / s;
  float* op = out + row * 6;
  #pragma unroll
  for (int j = 0; j < 5; j++) op[j] = e[j] * inv;
  op[5] = val;
}

// ---------------- per-graph attention + gat, writes feat cols 256..511 --------
// el/er arrive as Wh columns 250/251 (lane 62, q=2/3) — no reductions needed.
__global__ __launch_bounds__(256)
void attn_gat(const u16* __restrict__ Wh, u16* __restrict__ feat)
{
  const int w = threadIdx.x >> 6, lane = threadIdx.x & 63;
  const long g = (long)blockIdx.x * 4 + w;   // one wave per graph
  const int c0 = lane * 4;                    // 4 cols per lane (0..255)

  u64 raw[3][6];
  #pragma unroll
  for (int h = 0; h < 3; h++)
    #pragma unroll
    for (int i = 0; i < 6; i++)
      raw[h][i] = *(const u64*)(Wh + (((long)h * NROWS + g * 6 + i) << 8) + c0);

  float gacc[6][4];
  #pragma unroll
  for (int i = 0; i < 6; i++)
    #pragma unroll
    for (int q = 0; q < 4; q++) gacc[i][q] = 0.f;

  #pragma unroll
  for (int h = 0; h < 3; h++) {
    float whf[6][4];
    #pragma unroll
    for (int i = 0; i < 6; i++) {
      u64 v = raw[h][i];
      whf[i][0] = bf2f((u16)v);
      whf[i][1] = bf2f((u16)(v >> 16));
      whf[i][2] = bf2f((u16)(v >> 32));
      whf[i][3] = bf2f((u16)(v >> 48));
    }
    float el[6], er[6];
    #pragma unroll
    for (int i = 0; i < 6; i++) {
      el[i] = __shfl(whf[i][2], 62, 64);   // col 250
      er[i] = __shfl(whf[i][3], 62, 64);   // col 251
    }
    #pragma unroll
    for (int i = 0; i < 6; i++) {
      float e[6]; float mx = -1e30f;
      #pragma unroll
      for (int j = 0; j < 6; j++) {
        float t = el[i] + er[j];
        t = (t > 0.f) ? t : 0.2f * t;      // leaky_relu 0.2
        e[j] = t; mx = fmaxf(mx, t);
      }
      float s = 0.f;
      #pragma unroll
      for (int j = 0; j < 6; j++) { e[j] = __expf(e[j] - mx); s += e[j]; }
      float inv = 1.f / s;
      #pragma unroll
      for (int j = 0; j < 6; j++) {
        float a = e[j] * inv;
        #pragma unroll
        for (int q = 0; q < 4; q++) gacc[i][q] += a * whf[j][q];
      }
    }
  }
  #pragma unroll
  for (int i = 0; i < 6; i++) {
    const float k = 1.f / 3.f;
    u64 o = (u64)f2bf(gacc[i][0] * k)
          | ((u64)f2bf(gacc[i][1] * k) << 16)
          | ((u64)f2bf(gacc[i][2] * k) << 32)
          | ((u64)f2bf(gacc[i][3] * k) << 48);
    *(u64*)(feat + (g * 6 + i) * LDF + 256 + c0) = o;
  }
}

// ---------------- launch ----------------
extern "C" void kernel_launch(void* const* d_in, const int* in_sizes, int n_in,
                              void* d_out, int out_size, void* d_ws, size_t ws_size,
                              hipStream_t stream)
{
  const float* x     = (const float*)d_in[0];
  const float* W_emb = (const float*)d_in[1];
  const float* b_emb = (const float*)d_in[2];
  const float* W_gat = (const float*)d_in[3];
  const float* a_l   = (const float*)d_in[4];
  const float* a_r   = (const float*)d_in[5];
  const float* W1    = (const float*)d_in[6];
  const float* b1    = (const float*)d_in[7];
  const float* W2    = (const float*)d_in[8];
  const float* b2    = (const float*)d_in[9];
  const float* V1    = (const float*)d_in[10];
  const float* vb1   = (const float*)d_in[11];
  const float* V2    = (const float*)d_in[12];
  const float* vb2   = (const float*)d_in[13];

  char* ws = (char*)d_ws;
  u16* feat = (u16*)ws;                       // [98304][512] bf16 = 100,663,296 B
  char* r2  = ws + 100663296L;                // shared region, lifetimes disjoint:
  u16*   Whb      = (u16*)r2;                 //   [3][98304][256] (gemm2 -> attn)
  float* partials = (float*)r2;               //   [4][98304][6] fp32 (gemm3p -> final)
  char* wt  = r2 + 150994944L;
  u16*   Wemb_t = (u16*)wt;                   // 256*128
  u16*   Wgat_t = (u16*)(wt + 65536);         // 3*256*256
  u16*   W1V1_t = (u16*)(wt + 458752);        // 512*512
  float* b1vb1  = (float*)(wt + 983040);      // 512
  float* bembp  = (float*)(wt + 985088);      // 256

  prep_weights<<<256, 256, 0, stream>>>(W_emb, b_emb, W_gat, a_l, a_r, W1, b1, V1, vb1,
                                        Wemb_t, Wgat_t, W1V1_t, bembp, b1vb1);
  // h = relu(x @ W_emb + b) -> feat[:,0:256]  (fused fp32->bf16 conversion)
  gemm1f<<<dim3(768, 2), 256, 0, stream>>>(x, Wemb_t, feat, bembp);
  // Wh[h] = h @ W_gat[h]  (y -> z*2+n); cols 250/251 = el/er
  gemm_bf16<4><<<dim3(768, 6), 256, 0, stream>>>(feat, 512, Wgat_t, 256, 65536L,
                                                 Whb, 256, 25165824L);
  // attention + gat -> feat[:,256:512]
  attn_gat<<<4096, 256, 0, stream>>>(Whb, feat);
  // hidden = relu(feat @ [W1|V1] + b) folded into per-block head partials
  gemm3p<<<dim3(768, 4), 256, 0, stream>>>(feat, W1V1_t, b1vb1, W2, V2, partials);
  // sum partials, softmax | value
  heads_final<<<384, 256, 0, stream>>>(partials, b2, vb2, (float*)d_out);
}

// Round 9
// 351.994 us; speedup vs baseline: 1.0911x; 1.0911x over previous
//
#include <hip/hip_runtime.h>

typedef unsigned short u16;
typedef unsigned int   u32;
typedef unsigned long long u64;
typedef __attribute__((ext_vector_type(4))) int   i32x4;
typedef __attribute__((ext_vector_type(4))) float f32x4;
typedef __attribute__((ext_vector_type(8))) short s16x8;

#define NROWS 98304L   // B*A
#define LDF   512      // feat row stride (250 h | 6 pad | 250 gat | 6 pad)

__device__ __forceinline__ u16 f2bf(float x) {
  union { float f; u32 u; } v; v.f = x;
  return (u16)((v.u + 0x7FFFu + ((v.u >> 16) & 1u)) >> 16);
}
__device__ __forceinline__ float bf2f(u16 b) {
  union { float f; u32 u; } v; v.u = ((u32)b) << 16;
  return v.f;
}

// async global->LDS, 16B per lane; LDS dest = wave-uniform base + lane*16 (m104)
__device__ __forceinline__ void gload_lds16(const u16* g, u16* l) {
  __builtin_amdgcn_global_load_lds(
      (const __attribute__((address_space(1))) unsigned int*)g,
      (__attribute__((address_space(3))) unsigned int*)l, 16, 0, 0);
}

// ---------------- weight prep: transpose + zero-pad to bf16 ----------------
// Wgat_t rows e=250/251 get u_l[h]=W_gat[h]@a_l[h], u_r[h] so the Wh GEMM
// emits el/er as free output columns (el = h . (W_gat @ a_l)).
__global__ __launch_bounds__(256)
void prep_weights(const float* __restrict__ W_emb, const float* __restrict__ b_emb,
                  const float* __restrict__ W_gat, const float* __restrict__ a_l,
                  const float* __restrict__ a_r, const float* __restrict__ W1,
                  const float* __restrict__ b1, const float* __restrict__ V1,
                  const float* __restrict__ vb1,
                  u16* __restrict__ Wemb_t, u16* __restrict__ Wgat_t,
                  u16* __restrict__ W1V1_t, float* __restrict__ bembp,
                  float* __restrict__ b1vb1)
{
  const int idx = blockIdx.x * 256 + threadIdx.x;
  const int stride = gridDim.x * 256;
  // Wemb_t[n][k], n<256 (pad 250..255), k<128
  for (int t = idx; t < 256 * 128; t += stride) {
    int n = t >> 7, k = t & 127;
    Wemb_t[t] = f2bf(n < 250 ? W_emb[k * 250 + n] : 0.f);
  }
  // Wgat_t[h][e][d] = W_gat[h][d][e] (256x256 padded); rows 250/251 = u_l/u_r
  for (int t = idx; t < 3 * 256 * 256; t += stride) {
    int h = t >> 16, rem = t & 65535, e = rem >> 8, d = rem & 255;
    float v = 0.f;
    if (e < 250 && d < 250) {
      v = W_gat[(h * 250 + d) * 250 + e];
    } else if ((e == 250 || e == 251) && d < 250) {
      const float* av = ((e == 250) ? a_l : a_r) + h * 250;
      const float* wrow = W_gat + ((long)h * 250 + d) * 250;
      float s = 0.f;
      for (int q = 0; q < 250; q++) s += wrow[q] * av[q];
      v = s;
    }
    Wgat_t[t] = f2bf(v);
  }
  // W1V1_t[n][k]: n<256 actor col, else critic col; k maps feat-pad rows
  for (int t = idx; t < 512 * 512; t += stride) {
    int n = t >> 9, k = t & 511;
    const float* src = (n < 256) ? W1 : V1;
    int col = n & 255;
    float v = 0.f;
    if (k < 250) v = src[k * 256 + col];
    else if (k >= 256 && k < 506) v = src[(k - 6) * 256 + col];
    W1V1_t[t] = f2bf(v);
  }
  for (int t = idx; t < 512; t += stride) b1vb1[t] = (t < 256) ? b1[t] : vb1[t - 256];
  for (int t = idx; t < 256; t += stride) bembp[t] = (t < 250) ? b_emb[t] : 0.f;
}

// ---------------- gemm1f: fused x(fp32)->bf16 + embed GEMM ----------------
// C[128 x 128] tile of feat = relu(x @ Wemb_t^T + b). A reg-staged from fp32
// with conversion + swizzled ds_write (LDS[row][s] = chunk s^(row&7), same
// invariant as gload path); B via global_load_lds. grid (2, 768) n-fast.
__global__ __launch_bounds__(256, 2)
void gemm1f(const float* __restrict__ X,          // [NROWS][128] fp32
            const u16* __restrict__ B,            // Wemb_t [256][128]
            u16* __restrict__ C,                  // feat, ldc=512
            const float* __restrict__ bias)       // bembp [256]
{
  __shared__ __align__(16) u16 At[128 * 64];
  __shared__ __align__(16) u16 Bt[128 * 64];
  const int tid = threadIdx.x;
  const int w = tid >> 6, lane = tid & 63;
  const int fl = lane & 15, fh = lane >> 4;
  const int wr = (w >> 1) * 64, wc = (w & 1) * 64;
  const int srow = lane >> 3;                    // 0..7
  const int slot = lane & 7;                     // 0..7
  const int schunk = ((slot ^ srow) << 3);       // source chunk (elems)
  const int swz = (fl & 7) << 3;

  const int nidx = blockIdx.x;                   // 0..1
  const int midx = blockIdx.y;                   // 0..767

  const float* Ax = X + (long)midx * 128 * 128;
  const u16* Bb = B + nidx * 128 * 128;
  u16* Cb = C + (long)midx * 128 * LDF + nidx * 128;
  const float* biasb = bias + nidx * 128;

  f32x4 acc[4][4];
  #pragma unroll
  for (int m = 0; m < 4; m++)
    #pragma unroll
    for (int n = 0; n < 4; n++)
      acc[m][n] = f32x4{0.f, 0.f, 0.f, 0.f};

  for (int ks = 0; ks < 2; ks++) {
    __syncthreads();
    #pragma unroll
    for (int c = 0; c < 4; c++) {
      const int row = w * 32 + c * 8 + srow;
      // B: async global->LDS
      gload_lds16(Bb + (long)row * 128 + ks * 64 + schunk, Bt + (w * 4 + c) * 512);
      // A: fp32 load -> bf16 pack -> swizzled ds_write
      const float* src = Ax + (long)row * 128 + ks * 64 + schunk;
      f32x4 lo = *(const f32x4*)src;
      f32x4 hi = *(const f32x4*)(src + 4);
      i32x4 o;
      o[0] = (int)((u32)f2bf(lo[0]) | ((u32)f2bf(lo[1]) << 16));
      o[1] = (int)((u32)f2bf(lo[2]) | ((u32)f2bf(lo[3]) << 16));
      o[2] = (int)((u32)f2bf(hi[0]) | ((u32)f2bf(hi[1]) << 16));
      o[3] = (int)((u32)f2bf(hi[2]) | ((u32)f2bf(hi[3]) << 16));
      *(i32x4*)(At + row * 64 + slot * 8) = o;
    }
    __syncthreads();
    #pragma unroll
    for (int kk = 0; kk < 2; kk++) {
      s16x8 af[4], bfr[4];
      #pragma unroll
      for (int m = 0; m < 4; m++)
        af[m] = *(const s16x8*)(At + (wr + m * 16 + fl) * 64 + ((kk * 32 + fh * 8) ^ swz));
      #pragma unroll
      for (int n = 0; n < 4; n++)
        bfr[n] = *(const s16x8*)(Bt + (wc + n * 16 + fl) * 64 + ((kk * 32 + fh * 8) ^ swz));
      #pragma unroll
      for (int m = 0; m < 4; m++)
        #pragma unroll
        for (int n = 0; n < 4; n++)
          acc[m][n] = __builtin_amdgcn_mfma_f32_16x16x32_bf16(af[m], bfr[n], acc[m][n], 0, 0, 0);
    }
  }
  #pragma unroll
  for (int m = 0; m < 4; m++) {
    const int r0 = wr + m * 16 + fh * 4;
    #pragma unroll
    for (int n = 0; n < 4; n++) {
      const int col = wc + n * 16 + fl;
      const float bvv = biasb[col];
      f32x4 v = acc[m][n];
      #pragma unroll
      for (int r = 0; r < 4; r++)
        Cb[(long)(r0 + r) * LDF + col] = f2bf(fmaxf(v[r] + bvv, 0.f));
    }
  }
}

// ---------------- bf16 GEMM (gemm2): C = A * Bt^T, raw bf16 store ----------
// BM=BN=128, BK=64, 256 threads. Grid (nb*nz, mblocks) n-fast: consecutive
// blocks share the A-tile. global_load_lds staging, both-sides XOR swizzle.
template<int KSTEPS>
__global__ __launch_bounds__(256, 2)
void gemm_bf16(const u16* __restrict__ A, int lda,
               const u16* __restrict__ B, int ldb, long strideB,
               u16* __restrict__ C, int ldc, long strideC, int nb)
{
  __shared__ __align__(16) u16 At[128 * 64];
  __shared__ __align__(16) u16 Bt[128 * 64];
  const int tid = threadIdx.x;
  const int w = tid >> 6, lane = tid & 63;
  const int fl = lane & 15, fh = lane >> 4;
  const int wr = (w >> 1) * 64, wc = (w & 1) * 64;
  const int srow = lane >> 3;
  const int scol = (((lane & 7) ^ srow) << 3);
  const int swz = (fl & 7) << 3;

  const int nidx = blockIdx.x % nb;
  const int zidx = blockIdx.x / nb;
  const int midx = blockIdx.y;

  const u16* Ab = A + (long)midx * 128 * lda;
  const u16* Bb = B + (long)zidx * strideB + (long)nidx * 128 * ldb;
  u16* Cb = C + (long)zidx * strideC + (long)midx * 128 * ldc + nidx * 128;

  f32x4 acc[4][4];
  #pragma unroll
  for (int m = 0; m < 4; m++)
    #pragma unroll
    for (int n = 0; n < 4; n++)
      acc[m][n] = f32x4{0.f, 0.f, 0.f, 0.f};

  for (int ks = 0; ks < KSTEPS; ks++) {
    __syncthreads();
    #pragma unroll
    for (int c = 0; c < 4; c++) {
      const int row = w * 32 + c * 8 + srow;
      gload_lds16(Ab + (long)row * lda + ks * 64 + scol, At + (w * 4 + c) * 512);
      gload_lds16(Bb + (long)row * ldb + ks * 64 + scol, Bt + (w * 4 + c) * 512);
    }
    __syncthreads();
    #pragma unroll
    for (int kk = 0; kk < 2; kk++) {
      s16x8 af[4], bfr[4];
      #pragma unroll
      for (int m = 0; m < 4; m++)
        af[m] = *(const s16x8*)(At + (wr + m * 16 + fl) * 64 + ((kk * 32 + fh * 8) ^ swz));
      #pragma unroll
      for (int n = 0; n < 4; n++)
        bfr[n] = *(const s16x8*)(Bt + (wc + n * 16 + fl) * 64 + ((kk * 32 + fh * 8) ^ swz));
      #pragma unroll
      for (int m = 0; m < 4; m++)
        #pragma unroll
        for (int n = 0; n < 4; n++)
          acc[m][n] = __builtin_amdgcn_mfma_f32_16x16x32_bf16(af[m], bfr[n], acc[m][n], 0, 0, 0);
    }
  }
  #pragma unroll
  for (int m = 0; m < 4; m++) {
    const int r0 = wr + m * 16 + fh * 4;
    #pragma unroll
    for (int n = 0; n < 4; n++) {
      const int col = wc + n * 16 + fl;
      f32x4 v = acc[m][n];
      #pragma unroll
      for (int r = 0; r < 4; r++)
        Cb[(long)(r0 + r) * ldc + col] = f2bf(v[r]);
    }
  }
}

// ---------------- gemm3p: feat @ [W1|V1] with partial-heads epilogue -------
// Single-buffered 128x128 GEMM (round-4 proven loop). launch_bounds(256,4)
// caps total regs at 128 (64 acc AGPR + <=64 arch) -> 4 waves/SIMD; the
// round-7 version at 68+64=132 fell off the occupancy cliff (Occ 24%).
// Epilogue register-lean: per-m hidv computed once, j-outer, one W2 scalar
// live at a time. grid (768, 4) m-fast.
__global__ __launch_bounds__(256, 4)
void gemm3p(const u16* __restrict__ A,            // feat [NROWS][512]
            const u16* __restrict__ B,            // W1V1_t [512][512]
            const float* __restrict__ b1vb1,      // [512]
            const float* __restrict__ W2,         // [256][5]
            const float* __restrict__ V2,         // [256]
            float* __restrict__ partials)         // [4][NROWS][6]
{
  __shared__ __align__(16) u16 At[128 * 64];
  __shared__ __align__(16) u16 Bt[128 * 64];
  __shared__ float pstage[2][128][6];
  const int tid = threadIdx.x;
  const int w = tid >> 6, lane = tid & 63;
  const int fl = lane & 15, fh = lane >> 4;
  const int wr = (w >> 1) * 64, wc = (w & 1) * 64;
  const int wcid = w & 1;
  const int srow = lane >> 3;
  const int scol = (((lane & 7) ^ srow) << 3);
  const int swz = (fl & 7) << 3;

  const int midx = blockIdx.x;                   // 0..767
  const int nidx = blockIdx.y;                   // 0..3

  const u16* Ab = A + (long)midx * 128 * 512;
  const u16* Bb = B + (long)nidx * 128 * 512;

  f32x4 acc[4][4];
  #pragma unroll
  for (int m = 0; m < 4; m++)
    #pragma unroll
    for (int n = 0; n < 4; n++)
      acc[m][n] = f32x4{0.f, 0.f, 0.f, 0.f};

  for (int ks = 0; ks < 8; ks++) {
    __syncthreads();
    #pragma unroll
    for (int c = 0; c < 4; c++) {
      const int row = w * 32 + c * 8 + srow;
      gload_lds16(Ab + (long)row * 512 + ks * 64 + scol, At + (w * 4 + c) * 512);
      gload_lds16(Bb + (long)row * 512 + ks * 64 + scol, Bt + (w * 4 + c) * 512);
    }
    __syncthreads();
    #pragma unroll
    for (int kk = 0; kk < 2; kk++) {
      s16x8 af[4], bfr[4];
      #pragma unroll
      for (int m = 0; m < 4; m++)
        af[m] = *(const s16x8*)(At + (wr + m * 16 + fl) * 64 + ((kk * 32 + fh * 8) ^ swz));
      #pragma unroll
      for (int n = 0; n < 4; n++)
        bfr[n] = *(const s16x8*)(Bt + (wc + n * 16 + fl) * 64 + ((kk * 32 + fh * 8) ^ swz));
      #pragma unroll
      for (int m = 0; m < 4; m++)
        #pragma unroll
        for (int n = 0; n < 4; n++)
          acc[m][n] = __builtin_amdgcn_mfma_f32_16x16x32_bf16(af[m], bfr[n], acc[m][n], 0, 0, 0);
    }
  }

  // ---- partial-heads epilogue (register-lean) ----
  float bv[4];
  #pragma unroll
  for (int n = 0; n < 4; n++) bv[n] = b1vb1[nidx * 128 + wc + n * 16 + fl];

  #pragma unroll
  for (int m = 0; m < 4; m++) {
    float hidv[4][4];
    #pragma unroll
    for (int n = 0; n < 4; n++)
      #pragma unroll
      for (int r = 0; r < 4; r++)
        hidv[n][r] = fmaxf(acc[m][n][r] + bv[n], 0.f);
    const int row0 = wr + m * 16 + fh * 4;

    if (nidx < 2) {        // actor: hid cols nidx*128 + [0,128)
      #pragma unroll
      for (int j = 0; j < 5; j++) {
        float ps[4] = {0.f, 0.f, 0.f, 0.f};
        #pragma unroll
        for (int n = 0; n < 4; n++) {
          const float w2 = W2[(nidx * 128 + wc + n * 16 + fl) * 5 + j];
          #pragma unroll
          for (int r = 0; r < 4; r++) ps[r] += hidv[n][r] * w2;
        }
        #pragma unroll
        for (int off = 1; off < 16; off <<= 1)
          #pragma unroll
          for (int r = 0; r < 4; r++) ps[r] += __shfl_xor(ps[r], off, 16);
        if (fl == 0) {
          #pragma unroll
          for (int r = 0; r < 4; r++) pstage[wcid][row0 + r][j] = ps[r];
        }
      }
    } else {               // critic: hid cols nidx*128 + [0,128) - 256
      float ps[4] = {0.f, 0.f, 0.f, 0.f};
      #pragma unroll
      for (int n = 0; n < 4; n++) {
        const float v2c = V2[nidx * 128 + wc + n * 16 + fl - 256];
        #pragma unroll
        for (int r = 0; r < 4; r++) ps[r] += hidv[n][r] * v2c;
      }
      #pragma unroll
      for (int off = 1; off < 16; off <<= 1)
        #pragma unroll
        for (int r = 0; r < 4; r++) ps[r] += __shfl_xor(ps[r], off, 16);
      if (fl == 0) {
        #pragma unroll
        for (int r = 0; r < 4; r++) pstage[wcid][row0 + r][5] = ps[r];
      }
    }
  }
  __syncthreads();

  if (tid < 128) {
    float* dst = partials + ((long)nidx * NROWS + (long)midx * 128 + tid) * 6;
    if (nidx < 2) {
      #pragma unroll
      for (int j = 0; j < 5; j++)
        dst[j] = pstage[0][tid][j] + pstage[1][tid][j];
    } else {
      dst[5] = pstage[0][tid][5] + pstage[1][tid][5];
    }
  }
}

// ---------------- heads_final: sum partials, softmax | value ---------------
__global__ __launch_bounds__(256)
void heads_final(const float* __restrict__ partials, const float* __restrict__ b2,
                 const float* __restrict__ vb2, float* __restrict__ out)
{
  const long row = (long)blockIdx.x * 256 + threadIdx.x;
  const long slab = NROWS * 6;
  const float* p = partials + row * 6;
  float lg[5];
  #pragma unroll
  for (int j = 0; j < 5; j++) lg[j] = p[j] + p[slab + j] + b2[j];
  const float val = p[2 * slab + 5] + p[3 * slab + 5] + vb2[0];
  float mx = -1e30f;
  #pragma unroll
  for (int j = 0; j < 5; j++) mx = fmaxf(mx, lg[j]);
  float s = 0.f, e[5];
  #pragma unroll
  for (int j = 0; j < 5; j++) { e[j] = __expf(lg[j] - mx); s += e[j]; }
  const float inv = 1.f / s;
  float* op = out + row * 6;
  #pragma unroll
  for (int j = 0; j < 5; j++) op[j] = e[j] * inv;
  op[5] = val;
}

// ---------------- per-graph attention + gat, writes feat cols 256..511 --------
// el/er arrive as Wh columns 250/251 (lane 62, q=2/3) — no reductions needed.
__global__ __launch_bounds__(256)
void attn_gat(const u16* __restrict__ Wh, u16* __restrict__ feat)
{
  const int w = threadIdx.x >> 6, lane = threadIdx.x & 63;
  const long g = (long)blockIdx.x * 4 + w;   // one wave per graph
  const int c0 = lane * 4;                    // 4 cols per lane (0..255)

  u64 raw[3][6];
  #pragma unroll
  for (int h = 0; h < 3; h++)
    #pragma unroll
    for (int i = 0; i < 6; i++)
      raw[h][i] = *(const u64*)(Wh + (((long)h * NROWS + g * 6 + i) << 8) + c0);

  float gacc[6][4];
  #pragma unroll
  for (int i = 0; i < 6; i++)
    #pragma unroll
    for (int q = 0; q < 4; q++) gacc[i][q] = 0.f;

  #pragma unroll
  for (int h = 0; h < 3; h++) {
    float whf[6][4];
    #pragma unroll
    for (int i = 0; i < 6; i++) {
      u64 v = raw[h][i];
      whf[i][0] = bf2f((u16)v);
      whf[i][1] = bf2f((u16)(v >> 16));
      whf[i][2] = bf2f((u16)(v >> 32));
      whf[i][3] = bf2f((u16)(v >> 48));
    }
    float el[6], er[6];
    #pragma unroll
    for (int i = 0; i < 6; i++) {
      el[i] = __shfl(whf[i][2], 62, 64);   // col 250
      er[i] = __shfl(whf[i][3], 62, 64);   // col 251
    }
    #pragma unroll
    for (int i = 0; i < 6; i++) {
      float e[6]; float mx = -1e30f;
      #pragma unroll
      for (int j = 0; j < 6; j++) {
        float t = el[i] + er[j];
        t = (t > 0.f) ? t : 0.2f * t;      // leaky_relu 0.2
        e[j] = t; mx = fmaxf(mx, t);
      }
      float s = 0.f;
      #pragma unroll
      for (int j = 0; j < 6; j++) { e[j] = __expf(e[j] - mx); s += e[j]; }
      float inv = 1.f / s;
      #pragma unroll
      for (int j = 0; j < 6; j++) {
        float a = e[j] * inv;
        #pragma unroll
        for (int q = 0; q < 4; q++) gacc[i][q] += a * whf[j][q];
      }
    }
  }
  #pragma unroll
  for (int i = 0; i < 6; i++) {
    const float k = 1.f / 3.f;
    u64 o = (u64)f2bf(gacc[i][0] * k)
          | ((u64)f2bf(gacc[i][1] * k) << 16)
          | ((u64)f2bf(gacc[i][2] * k) << 32)
          | ((u64)f2bf(gacc[i][3] * k) << 48);
    *(u64*)(feat + (g * 6 + i) * LDF + 256 + c0) = o;
  }
}

// ---------------- launch ----------------
extern "C" void kernel_launch(void* const* d_in, const int* in_sizes, int n_in,
                              void* d_out, int out_size, void* d_ws, size_t ws_size,
                              hipStream_t stream)
{
  const float* x     = (const float*)d_in[0];
  const float* W_emb = (const float*)d_in[1];
  const float* b_emb = (const float*)d_in[2];
  const float* W_gat = (const float*)d_in[3];
  const float* a_l   = (const float*)d_in[4];
  const float* a_r   = (const float*)d_in[5];
  const float* W1    = (const float*)d_in[6];
  const float* b1    = (const float*)d_in[7];
  const float* W2    = (const float*)d_in[8];
  const float* b2    = (const float*)d_in[9];
  const float* V1    = (const float*)d_in[10];
  const float* vb1   = (const float*)d_in[11];
  const float* V2    = (const float*)d_in[12];
  const float* vb2   = (const float*)d_in[13];

  char* ws = (char*)d_ws;
  u16* feat = (u16*)ws;                       // [98304][512] bf16 = 100,663,296 B
  char* r2  = ws + 100663296L;                // shared region, lifetimes disjoint:
  u16*   Whb      = (u16*)r2;                 //   [3][98304][256] (gemm2 -> attn)
  float* partials = (float*)r2;               //   [4][98304][6] fp32 (gemm3p -> final)
  char* wt  = r2 + 150994944L;
  u16*   Wemb_t = (u16*)wt;                   // 256*128
  u16*   Wgat_t = (u16*)(wt + 65536);         // 3*256*256
  u16*   W1V1_t = (u16*)(wt + 458752);        // 512*512
  float* b1vb1  = (float*)(wt + 983040);      // 512
  float* bembp  = (float*)(wt + 985088);      // 256

  prep_weights<<<256, 256, 0, stream>>>(W_emb, b_emb, W_gat, a_l, a_r, W1, b1, V1, vb1,
                                        Wemb_t, Wgat_t, W1V1_t, bembp, b1vb1);
  // h = relu(x @ W_emb + b) -> feat[:,0:256]  (fused fp32->bf16 conversion)
  gemm1f<<<dim3(2, 768), 256, 0, stream>>>(x, Wemb_t, feat, bembp);
  // Wh[h] = h @ W_gat[h]  (x = n+z packed, nb=2); cols 250/251 = el/er
  gemm_bf16<4><<<dim3(6, 768), 256, 0, stream>>>(feat, 512, Wgat_t, 256, 65536L,
                                                 Whb, 256, 25165824L, 2);
  // attention + gat -> feat[:,256:512]
  attn_gat<<<4096, 256, 0, stream>>>(Whb, feat);
  // hidden = relu(feat @ [W1|V1] + b) folded into per-block head partials
  gemm3p<<<dim3(768, 4), 256, 0, stream>>>(feat, W1V1_t, b1vb1, W2, V2, partials);
  // sum partials, softmax | value
  heads_final<<<384, 256, 0, stream>>>(partials, b2, vb2, (float*)d_out);
}